// Round 9
// baseline (267.610 us; speedup 1.0000x reference)
//
#include <hip/hip_runtime.h>

#define D 128
#define NG 64
#define NC 16
#define NEG 0.1f

typedef __attribute__((ext_vector_type(8))) short bf16x8;
typedef __attribute__((ext_vector_type(4))) float f32x4;

// ---------- bf16 <-> fp32 helpers (bf16 stored as ushort, packed pairs in uint) ----------
__device__ __forceinline__ float bf2f(unsigned int u16) {
    union { unsigned int i; float f; } c;
    c.i = u16 << 16;
    return c.f;
}
__device__ __forceinline__ unsigned short f2bf(float f) {
    union { float f; unsigned int i; } c;
    c.f = f;
    unsigned int i = c.i;
    unsigned int r = (i + 0x7FFFu + ((i >> 16) & 1u)) >> 16;  // RNE
    return (unsigned short)r;
}

// ---------------- fused prep + layer-1 GEMM (R7-verified) ----------------
// blocks [0, gb): layer-1 MFMA GEMM (W1 image built in-block in LDS).
// blocks [gb, gb+8): W2 -> Wf2 fragment-order image. [gb+8, ...): degree histogram.
// gemm1 runs concurrently with the histogram.
__global__ __launch_bounds__(256) void prep_gemm1_kernel(
        const float* __restrict__ x, const float* __restrict__ W1,
        unsigned int* __restrict__ C, int gb,
        const float* __restrict__ W2, unsigned short* __restrict__ Wf2,
        const int* __restrict__ dst, int* __restrict__ deg, int E, int N) {
    __shared__ uint4 Ws[2048];  // 32 KB, fragment-order image (gemm blocks only)
    int b = blockIdx.x;
    int tid = threadIdx.x;
    if (b < gb) {
        int w = tid >> 6, lane = tid & 63;
        int quad = lane >> 4, m16 = lane & 15;
        int rowstart = b * 64;
#pragma unroll
        for (int i = 0; i < 8; i++) {
            int fid = tid + 256 * i;
            int fm = fid & 15;
            int fquad = (fid >> 4) & 3;
            int fkc = (fid >> 6) & 3;
            int ft = fid >> 8;
            int n = ft * 16 + fm;
            int k0 = fkc * 32 + fquad * 8;
            unsigned short r[8];
#pragma unroll
            for (int j = 0; j < 8; j++) r[j] = f2bf(W1[(k0 + j) * 128 + n]);
            uint4 v;
            v.x = (unsigned int)r[0] | ((unsigned int)r[1] << 16);
            v.y = (unsigned int)r[2] | ((unsigned int)r[3] << 16);
            v.z = (unsigned int)r[4] | ((unsigned int)r[5] << 16);
            v.w = (unsigned int)r[6] | ((unsigned int)r[7] << 16);
            Ws[fid] = v;
        }

        int arow = rowstart + 16 * w + m16;
        bool valid = arow < N;
        bf16x8 af[4];
#pragma unroll
        for (int kc = 0; kc < 4; kc++) {
            float4 f0 = make_float4(0.f, 0.f, 0.f, 0.f), f1 = f0;
            if (valid) {
                const float4* p = (const float4*)(x + (size_t)arow * 128 + kc * 32 + quad * 8);
                f0 = p[0];
                f1 = p[1];
            }
            bf16x8 a;
            a[0] = (short)f2bf(f0.x); a[1] = (short)f2bf(f0.y);
            a[2] = (short)f2bf(f0.z); a[3] = (short)f2bf(f0.w);
            a[4] = (short)f2bf(f1.x); a[5] = (short)f2bf(f1.y);
            a[6] = (short)f2bf(f1.z); a[7] = (short)f2bf(f1.w);
            af[kc] = a;
        }
        __syncthreads();

        f32x4 acc[8];
#pragma unroll
        for (int t = 0; t < 8; t++) acc[t] = (f32x4){0.f, 0.f, 0.f, 0.f};
#pragma unroll
        for (int t = 0; t < 8; t++) {
#pragma unroll
            for (int kc = 0; kc < 4; kc++) {
                bf16x8 bh = *(const bf16x8*)&Ws[(((t * 4 + kc) * 4 + quad) * 16 + m16)];
                acc[t] = __builtin_amdgcn_mfma_f32_16x16x32_bf16(af[kc], bh, acc[t], 0, 0, 0);
            }
        }
#pragma unroll
        for (int t = 0; t < 8; t++) {
#pragma unroll
            for (int r = 0; r < 4; r++) {
                int row = rowstart + 16 * w + quad * 4 + r;
                unsigned int us = f2bf(acc[t][r]);
                unsigned int other = (unsigned int)__shfl_xor((int)us, 1);
                if (((m16 & 1) == 0) && row < N)
                    C[(size_t)row * 64 + t * 8 + (m16 >> 1)] = us | (other << 16);
            }
        }
    } else {
        int bb = b - gb;
        if (bb < 8) {
            int fid = bb * 256 + tid;
            int m = fid & 15;
            int quad = (fid >> 4) & 3;
            int kc = (fid >> 6) & 3;
            int t = fid >> 8;
            int n = t * 16 + m;
            int k0 = kc * 32 + quad * 8;
            unsigned short r[8];
#pragma unroll
            for (int j = 0; j < 8; j++) r[j] = f2bf(W2[(k0 + j) * 128 + n]);
            uint4 v;
            v.x = (unsigned int)r[0] | ((unsigned int)r[1] << 16);
            v.y = (unsigned int)r[2] | ((unsigned int)r[3] << 16);
            v.z = (unsigned int)r[4] | ((unsigned int)r[5] << 16);
            v.w = (unsigned int)r[6] | ((unsigned int)r[7] << 16);
            ((uint4*)Wf2)[fid] = v;
        } else {
            int e = (bb - 8) * 256 + tid;
            if (e < E) atomicAdd(&deg[dst[e]], 1);
        }
    }
}

// ---------------- fused scan + finalize: decoupled lookback ----------------
// One kernel (nscan <= 256 blocks, all co-resident on 256 CUs -> spin is deadlock-free).
// Each block scans its 256 deg in LDS, publishes (aggregate | 1<<31) via one device-scope
// atomicExch into memset-zeroed flagagg[], then lane-parallel spins on its predecessors,
// LDS-reduces their aggregates, and writes ptr/fill (+dinv) directly. Aggregate rides in
// the same 32-bit word as the ready-bit (E < 2^31), so no separate fence is needed.
__global__ __launch_bounds__(256) void scanfin_kernel(const int* __restrict__ deg,
                                                      unsigned int* __restrict__ flagagg,
                                                      int* __restrict__ ptr,
                                                      int* __restrict__ fill,
                                                      float* __restrict__ dinv, int N, int E) {
    __shared__ int sm[256];
    int tid = threadIdx.x;
    int blk = blockIdx.x;
    int i = blk * 256 + tid;
    int v = (i < N) ? deg[i] : 0;
    if (i < N) dinv[i] = 1.0f / sqrtf((float)v + 1.0f);
    sm[tid] = v;
    __syncthreads();
    for (int off = 1; off < 256; off <<= 1) {
        int t = (tid >= off) ? sm[tid - off] : 0;
        __syncthreads();
        sm[tid] += t;
        __syncthreads();
    }
    int incl = sm[tid];
    if (tid == 0)
        atomicExch(&flagagg[blk], (unsigned int)sm[255] | 0x80000000u);
    __syncthreads();
    // lookback: thread t (< blk) spins on block t's word
    unsigned int a = 0;
    if (tid < blk) {
        unsigned int w;
        do {
            w = (unsigned int)atomicAdd((int*)&flagagg[tid], 0);
        } while (!(w & 0x80000000u));
        a = w & 0x7fffffffu;
    }
    sm[tid] = (int)a;
    __syncthreads();
    for (int off = 128; off > 0; off >>= 1) {
        if (tid < off) sm[tid] += sm[tid + off];
        __syncthreads();
    }
    int blockoff = sm[0];
    if (i < N) {
        int p = incl - v + blockoff;  // exclusive prefix
        ptr[i] = p;
        fill[i] = p;  // scatter cursor
        if (i == N - 1) ptr[N] = E;
    }
}

// ---------------- scatter edges into CSR by dst; packed (src, coef) int2 ----------------
__global__ void scatter_kernel(const int* __restrict__ src, const int* __restrict__ dst,
                               int* __restrict__ fill, const float* __restrict__ dinv,
                               int2* __restrict__ csr_edge, int E) {
    int e = blockIdx.x * blockDim.x + threadIdx.x;
    if (e < E) {
        int d = dst[e];
        int s = src[e];
        int pos = atomicAdd(&fill[d], 1);
        float coef = dinv[s] * dinv[d];
        csr_edge[pos] = make_int2(s, __float_as_int(coef));
    }
}

#define ACC8(v, c)                                                         \
    a0 += bf2f((v).x & 0xffffu) * (c); a1 += bf2f((v).x >> 16) * (c);      \
    a2 += bf2f((v).y & 0xffffu) * (c); a3 += bf2f((v).y >> 16) * (c);      \
    a4 += bf2f((v).z & 0xffffu) * (c); a5 += bf2f((v).z >> 16) * (c);      \
    a6 += bf2f((v).w & 0xffffu) * (c); a7 += bf2f((v).w >> 16) * (c);

// ---------------- FUSED combine(layer1) + gemm2 (R8-verified) ----------------
__global__ __launch_bounds__(256) void combine_gemm_kernel(
        const uint4* __restrict__ h4,       // G1 = x@W1 rows (packed bf16)
        const int* __restrict__ ptr,
        const int2* __restrict__ csr_edge,
        const float* __restrict__ dinv,
        const float* __restrict__ b,        // b1
        const uint4* __restrict__ Wf2,      // fragment-order W2 image
        unsigned int* __restrict__ C,       // out: (h1 @ W2) rows, packed bf16
        int N) {
    __shared__ int2 smeta[4][64];           // 2 KB edge strips
    __shared__ unsigned int rowt[16 * 68];  // 16 rows x 272 B padded h1 tile (4.25 KB)
    int wave = threadIdx.x >> 6;
    int lane = threadIdx.x & 63;
    int q = lane >> 4;
    int l16 = lane & 15;
    int bb = blockIdx.x * 16;
    int nb = bb + wave * 4;
    int node = nb + q;
    bool valid = node < N;

    if (nb < N) {  // predicated (no return: barrier below needs all waves)
        int wlo = ptr[nb];
        int whi = ptr[min(nb + 4, N)];
        int lo = valid ? ptr[node] : 0;
        int hi = valid ? ptr[node + 1] : 0;

        float di = valid ? dinv[node] : 0.f;
        uint4 sv = valid ? h4[(size_t)node * 16 + l16] : make_uint4(0u, 0u, 0u, 0u);
        float4 bv0 = ((const float4*)b)[l16 * 2];
        float4 bv1 = ((const float4*)b)[l16 * 2 + 1];

        float a0 = 0.f, a1 = 0.f, a2 = 0.f, a3 = 0.f, a4 = 0.f, a5 = 0.f, a6 = 0.f, a7 = 0.f;

#pragma unroll 1
        for (int base = wlo; base < whi; base += 64) {
            if (base + lane < whi) smeta[wave][lane] = csr_edge[base + lane];
            // wave-private strip: same-wave DS ordering suffices, no barrier
            int s = max(lo, base);
            int e = min(hi, base + 64);
            int j = s;
#pragma unroll 1
            for (; j + 3 < e; j += 4) {
                int k = j - base;
                int2 e0 = smeta[wave][k];
                int2 e1 = smeta[wave][k + 1];
                int2 e2 = smeta[wave][k + 2];
                int2 e3 = smeta[wave][k + 3];
                uint4 v0 = h4[(size_t)e0.x * 16 + l16];
                uint4 v1 = h4[(size_t)e1.x * 16 + l16];
                uint4 v2 = h4[(size_t)e2.x * 16 + l16];
                uint4 v3 = h4[(size_t)e3.x * 16 + l16];
                float c0 = __int_as_float(e0.y);
                float c1 = __int_as_float(e1.y);
                float c2 = __int_as_float(e2.y);
                float c3 = __int_as_float(e3.y);
                ACC8(v0, c0)
                ACC8(v1, c1)
                ACC8(v2, c2)
                ACC8(v3, c3)
            }
#pragma unroll 1
            for (; j < e; j++) {
                int k = j - base;
                int2 e0 = smeta[wave][k];
                uint4 v0 = h4[(size_t)e0.x * 16 + l16];
                float c0 = __int_as_float(e0.y);
                ACC8(v0, c0)
            }
        }

        if (valid) {
            float dd = di * di;
            float v0 = a0 + bf2f(sv.x & 0xffffu) * dd + bv0.x;
            float v1 = a1 + bf2f(sv.x >> 16) * dd + bv0.y;
            float v2 = a2 + bf2f(sv.y & 0xffffu) * dd + bv0.z;
            float v3 = a3 + bf2f(sv.y >> 16) * dd + bv0.w;
            float v4 = a4 + bf2f(sv.z & 0xffffu) * dd + bv1.x;
            float v5 = a5 + bf2f(sv.z >> 16) * dd + bv1.y;
            float v6 = a6 + bf2f(sv.w & 0xffffu) * dd + bv1.z;
            float v7 = a7 + bf2f(sv.w >> 16) * dd + bv1.w;
            v0 = (v0 >= 0.f) ? v0 : NEG * v0;
            v1 = (v1 >= 0.f) ? v1 : NEG * v1;
            v2 = (v2 >= 0.f) ? v2 : NEG * v2;
            v3 = (v3 >= 0.f) ? v3 : NEG * v3;
            v4 = (v4 >= 0.f) ? v4 : NEG * v4;
            v5 = (v5 >= 0.f) ? v5 : NEG * v5;
            v6 = (v6 >= 0.f) ? v6 : NEG * v6;
            v7 = (v7 >= 0.f) ? v7 : NEG * v7;
            unsigned int* p = &rowt[(wave * 4 + q) * 68 + l16 * 4];
            p[0] = (unsigned int)f2bf(v0) | ((unsigned int)f2bf(v1) << 16);
            p[1] = (unsigned int)f2bf(v2) | ((unsigned int)f2bf(v3) << 16);
            p[2] = (unsigned int)f2bf(v4) | ((unsigned int)f2bf(v5) << 16);
            p[3] = (unsigned int)f2bf(v6) | ((unsigned int)f2bf(v7) << 16);
        }
    }
    __syncthreads();

    // ---- phase 2: 16x128 GEMM tile, h1(LDS) @ W2(global image) ----
#pragma unroll
    for (int tt = 0; tt < 2; tt++) {
        int t = wave * 2 + tt;
        f32x4 acc = (f32x4){0.f, 0.f, 0.f, 0.f};
#pragma unroll
        for (int kc = 0; kc < 4; kc++) {
            bf16x8 a = *(const bf16x8*)&rowt[l16 * 68 + kc * 16 + q * 4];
            bf16x8 bh = *(const bf16x8*)&Wf2[((t * 4 + kc) * 4 + q) * 16 + l16];
            acc = __builtin_amdgcn_mfma_f32_16x16x32_bf16(a, bh, acc, 0, 0, 0);
        }
#pragma unroll
        for (int r = 0; r < 4; r++) {
            int row = bb + q * 4 + r;
            unsigned int us = f2bf(acc[r]);
            unsigned int other = (unsigned int)__shfl_xor((int)us, 1);
            if (((l16 & 1) == 0) && row < N)
                C[(size_t)row * 64 + t * 8 + (l16 >> 1)] = us | (other << 16);
        }
    }
}

// ---------------- gather + self-loop + bias + leaky_relu (layer 2; R1-verified) -------------
__global__ __launch_bounds__(256) void combine_kernel(const uint4* __restrict__ h4,
                                                      const int* __restrict__ ptr,
                                                      const int2* __restrict__ csr_edge,
                                                      const float* __restrict__ dinv,
                                                      const float* __restrict__ b,
                                                      uint4* __restrict__ out4, int N) {
    __shared__ int2 smeta[4][64];
    int wave = threadIdx.x >> 6;
    int lane = threadIdx.x & 63;
    int q = lane >> 4;
    int l16 = lane & 15;
    int nb = blockIdx.x * 16 + wave * 4;
    if (nb >= N) return;  // wave-uniform exit; kernel uses no barriers
    int node = nb + q;
    bool valid = node < N;

    int wlo = ptr[nb];
    int whi = ptr[min(nb + 4, N)];
    int lo = valid ? ptr[node] : 0;
    int hi = valid ? ptr[node + 1] : 0;

    float di = valid ? dinv[node] : 0.f;
    uint4 sv = valid ? h4[(size_t)node * 16 + l16] : make_uint4(0u, 0u, 0u, 0u);
    float4 bv0 = ((const float4*)b)[l16 * 2];
    float4 bv1 = ((const float4*)b)[l16 * 2 + 1];

    float a0 = 0.f, a1 = 0.f, a2 = 0.f, a3 = 0.f, a4 = 0.f, a5 = 0.f, a6 = 0.f, a7 = 0.f;

#pragma unroll 1
    for (int base = wlo; base < whi; base += 64) {
        if (base + lane < whi) smeta[wave][lane] = csr_edge[base + lane];
        int s = max(lo, base);
        int e = min(hi, base + 64);
        int j = s;
#pragma unroll 1
        for (; j + 3 < e; j += 4) {
            int k = j - base;
            int2 e0 = smeta[wave][k];
            int2 e1 = smeta[wave][k + 1];
            int2 e2 = smeta[wave][k + 2];
            int2 e3 = smeta[wave][k + 3];
            uint4 v0 = h4[(size_t)e0.x * 16 + l16];
            uint4 v1 = h4[(size_t)e1.x * 16 + l16];
            uint4 v2 = h4[(size_t)e2.x * 16 + l16];
            uint4 v3 = h4[(size_t)e3.x * 16 + l16];
            float c0 = __int_as_float(e0.y);
            float c1 = __int_as_float(e1.y);
            float c2 = __int_as_float(e2.y);
            float c3 = __int_as_float(e3.y);
            ACC8(v0, c0)
            ACC8(v1, c1)
            ACC8(v2, c2)
            ACC8(v3, c3)
        }
#pragma unroll 1
        for (; j < e; j++) {
            int k = j - base;
            int2 e0 = smeta[wave][k];
            uint4 v0 = h4[(size_t)e0.x * 16 + l16];
            float c0 = __int_as_float(e0.y);
            ACC8(v0, c0)
        }
    }

    if (!valid) return;
    float dd = di * di;
    float v0 = a0 + bf2f(sv.x & 0xffffu) * dd + bv0.x;
    float v1 = a1 + bf2f(sv.x >> 16) * dd + bv0.y;
    float v2 = a2 + bf2f(sv.y & 0xffffu) * dd + bv0.z;
    float v3 = a3 + bf2f(sv.y >> 16) * dd + bv0.w;
    float v4 = a4 + bf2f(sv.z & 0xffffu) * dd + bv1.x;
    float v5 = a5 + bf2f(sv.z >> 16) * dd + bv1.y;
    float v6 = a6 + bf2f(sv.w & 0xffffu) * dd + bv1.z;
    float v7 = a7 + bf2f(sv.w >> 16) * dd + bv1.w;
    v0 = (v0 >= 0.f) ? v0 : NEG * v0;
    v1 = (v1 >= 0.f) ? v1 : NEG * v1;
    v2 = (v2 >= 0.f) ? v2 : NEG * v2;
    v3 = (v3 >= 0.f) ? v3 : NEG * v3;
    v4 = (v4 >= 0.f) ? v4 : NEG * v4;
    v5 = (v5 >= 0.f) ? v5 : NEG * v5;
    v6 = (v6 >= 0.f) ? v6 : NEG * v6;
    v7 = (v7 >= 0.f) ? v7 : NEG * v7;
    uint4 pv;
    pv.x = (unsigned int)f2bf(v0) | ((unsigned int)f2bf(v1) << 16);
    pv.y = (unsigned int)f2bf(v2) | ((unsigned int)f2bf(v3) << 16);
    pv.z = (unsigned int)f2bf(v4) | ((unsigned int)f2bf(v5) << 16);
    pv.w = (unsigned int)f2bf(v6) | ((unsigned int)f2bf(v7) << 16);
    out4[(size_t)node * 16 + l16] = pv;
}

// ---------------- fused pool + classifier: one block per graph ----------------
// Block g: binary-search its node range in sorted batch, stream its ~N/NG rows (lane owns
// feats 2*lane, 2*lane+1; 4 waves split rows), LDS-reduce to the pooled row, then 16
// threads compute out[g, :] = (pooled/cnt) @ Wl + bl. No atomics, no pooled buffer,
// no cross-block communication (R2/R3 atomic-storm lesson).
__global__ __launch_bounds__(256) void poolfinal_kernel(const unsigned int* __restrict__ a2,
                                                        const int* __restrict__ batch,
                                                        const float* __restrict__ Wl,
                                                        const float* __restrict__ bl,
                                                        float* __restrict__ out, int N) {
    __shared__ float psum[4][128];
    __shared__ float pl[128];
    int g = blockIdx.x;
    int tid = threadIdx.x;
    int wave = tid >> 6, lane = tid & 63;
    // node range [lo, hi) of graph g
    int l = 0, h = N;
    while (l < h) { int m = (l + h) >> 1; if (batch[m] < g) l = m + 1; else h = m; }
    int lo = l;
    h = N;
    while (l < h) { int m = (l + h) >> 1; if (batch[m] < g + 1) l = m + 1; else h = m; }
    int hi = l;
    int cnt = hi - lo;

    float s0 = 0.f, s1 = 0.f;
    for (int r = lo + wave; r < hi; r += 4) {
        unsigned int v = a2[(size_t)r * 64 + lane];
        s0 += bf2f(v & 0xffffu);
        s1 += bf2f(v >> 16);
    }
    psum[wave][2 * lane] = s0;
    psum[wave][2 * lane + 1] = s1;
    __syncthreads();
    if (tid < 128) pl[tid] = psum[0][tid] + psum[1][tid] + psum[2][tid] + psum[3][tid];
    __syncthreads();
    if (tid < NC) {
        float inv = 1.0f / (float)(cnt > 0 ? cnt : 1);
        float dot = 0.f;
        for (int k = 0; k < D; k++) dot += pl[k] * Wl[k * NC + tid];
        out[g * NC + tid] = dot * inv + bl[tid];
    }
}

extern "C" void kernel_launch(void* const* d_in, const int* in_sizes, int n_in,
                              void* d_out, int out_size, void* d_ws, size_t ws_size,
                              hipStream_t stream) {
    const float* x = (const float*)d_in[0];
    const int* ei = (const int*)d_in[1];
    const int* batch = (const int*)d_in[2];
    const float* W1 = (const float*)d_in[3];
    const float* b1 = (const float*)d_in[4];
    const float* W2 = (const float*)d_in[5];
    const float* b2 = (const float*)d_in[6];
    const float* Wlin = (const float*)d_in[7];
    const float* bl = (const float*)d_in[8];
    float* out = (float*)d_out;

    int N = in_sizes[0] / D;
    int E = in_sizes[1] / 2;
    const int* src = ei;
    const int* dst = ei + E;

    float* ws = (float*)d_ws;
    size_t o = 0;
    unsigned int* bufA = (unsigned int*)(ws + o); o += (size_t)N * 64;  // 12.8 MB
    unsigned int* bufB = (unsigned int*)(ws + o); o += (size_t)N * 64;  // 12.8 MB
    int* deg = (int*)(ws + o);      o += N;       // zeroed by memset (with flagagg)
    unsigned int* flagagg = (unsigned int*)(ws + o); o += 256;  // zeroed by memset
    int* fill = (int*)(ws + o);     o += N;
    float* dinv = ws + o;           o += N;
    int* csr_ptr = (int*)(ws + o);  o += (N + 4);
    int2* csr_edge = (int2*)(ws + o); o += (size_t)2 * E;
    unsigned short* Wf2 = (unsigned short*)(ws + o); o += 8192;

    // one memset covers deg[N] + flagagg[256] (contiguous)
    hipMemsetAsync(deg, 0, ((size_t)N + 256) * sizeof(int), stream);

    int tb = 256;
    int nscan = (N + 255) / 256;
    int gblocks = (N + 63) / 64;
    int cblocks = (N + 15) / 16;
    int eblocks = (E + 255) / 256;

    // fused: layer-1 GEMM || {Wf2 image, degree histogram}
    prep_gemm1_kernel<<<gblocks + 8 + eblocks, 256, 0, stream>>>(
        x, W1, (unsigned int*)bufA, gblocks, W2, Wf2, dst, deg, E, N);
    // fused scan+finalize (decoupled lookback)
    scanfin_kernel<<<nscan, 256, 0, stream>>>(deg, flagagg, csr_ptr, fill, dinv, N, E);
    scatter_kernel<<<(E + tb - 1) / tb, tb, 0, stream>>>(src, dst, fill, dinv,
                                                         csr_edge, E);
    // fused combine(layer1)+gemm2: bufA(G1) -> bufB(h1@W2)
    combine_gemm_kernel<<<cblocks, 256, 0, stream>>>((const uint4*)bufA, csr_ptr, csr_edge,
                                                     dinv, b1, (const uint4*)Wf2,
                                                     (unsigned int*)bufB, N);
    // layer-2 combine: bufB -> bufA
    combine_kernel<<<cblocks, 256, 0, stream>>>((const uint4*)bufB, csr_ptr, csr_edge,
                                                dinv, b2, (uint4*)bufA, N);
    // fused pool + classifier (one block per graph)
    poolfinal_kernel<<<NG, 256, 0, stream>>>(bufA, batch, Wlin, bl, out, N);
}

// Round 10
// 231.736 us; speedup vs baseline: 1.1548x; 1.1548x over previous
//
#include <hip/hip_runtime.h>

#define D 128
#define NG 64
#define NC 16
#define NEG 0.1f

typedef __attribute__((ext_vector_type(8))) short bf16x8;
typedef __attribute__((ext_vector_type(4))) float f32x4;

// ---------- bf16 <-> fp32 helpers (bf16 stored as ushort, packed pairs in uint) ----------
__device__ __forceinline__ float bf2f(unsigned int u16) {
    union { unsigned int i; float f; } c;
    c.i = u16 << 16;
    return c.f;
}
__device__ __forceinline__ unsigned short f2bf(float f) {
    union { float f; unsigned int i; } c;
    c.f = f;
    unsigned int i = c.i;
    unsigned int r = (i + 0x7FFFu + ((i >> 16) & 1u)) >> 16;  // RNE
    return (unsigned short)r;
}

// ---------------- fused prep + layer-1 GEMM (R7-verified) ----------------
// blocks [0, gb): layer-1 MFMA GEMM (W1 image built in-block in LDS).
// blocks [gb, gb+8): W2 -> Wf2 fragment-order image. [gb+8, ...): degree histogram.
__global__ __launch_bounds__(256) void prep_gemm1_kernel(
        const float* __restrict__ x, const float* __restrict__ W1,
        unsigned int* __restrict__ C, int gb,
        const float* __restrict__ W2, unsigned short* __restrict__ Wf2,
        const int* __restrict__ dst, int* __restrict__ deg, int E, int N) {
    __shared__ uint4 Ws[2048];  // 32 KB, fragment-order image (gemm blocks only)
    int b = blockIdx.x;
    int tid = threadIdx.x;
    if (b < gb) {
        int w = tid >> 6, lane = tid & 63;
        int quad = lane >> 4, m16 = lane & 15;
        int rowstart = b * 64;
#pragma unroll
        for (int i = 0; i < 8; i++) {
            int fid = tid + 256 * i;
            int fm = fid & 15;
            int fquad = (fid >> 4) & 3;
            int fkc = (fid >> 6) & 3;
            int ft = fid >> 8;
            int n = ft * 16 + fm;
            int k0 = fkc * 32 + fquad * 8;
            unsigned short r[8];
#pragma unroll
            for (int j = 0; j < 8; j++) r[j] = f2bf(W1[(k0 + j) * 128 + n]);
            uint4 v;
            v.x = (unsigned int)r[0] | ((unsigned int)r[1] << 16);
            v.y = (unsigned int)r[2] | ((unsigned int)r[3] << 16);
            v.z = (unsigned int)r[4] | ((unsigned int)r[5] << 16);
            v.w = (unsigned int)r[6] | ((unsigned int)r[7] << 16);
            Ws[fid] = v;
        }

        int arow = rowstart + 16 * w + m16;
        bool valid = arow < N;
        bf16x8 af[4];
#pragma unroll
        for (int kc = 0; kc < 4; kc++) {
            float4 f0 = make_float4(0.f, 0.f, 0.f, 0.f), f1 = f0;
            if (valid) {
                const float4* p = (const float4*)(x + (size_t)arow * 128 + kc * 32 + quad * 8);
                f0 = p[0];
                f1 = p[1];
            }
            bf16x8 a;
            a[0] = (short)f2bf(f0.x); a[1] = (short)f2bf(f0.y);
            a[2] = (short)f2bf(f0.z); a[3] = (short)f2bf(f0.w);
            a[4] = (short)f2bf(f1.x); a[5] = (short)f2bf(f1.y);
            a[6] = (short)f2bf(f1.z); a[7] = (short)f2bf(f1.w);
            af[kc] = a;
        }
        __syncthreads();

        f32x4 acc[8];
#pragma unroll
        for (int t = 0; t < 8; t++) acc[t] = (f32x4){0.f, 0.f, 0.f, 0.f};
#pragma unroll
        for (int t = 0; t < 8; t++) {
#pragma unroll
            for (int kc = 0; kc < 4; kc++) {
                bf16x8 bh = *(const bf16x8*)&Ws[(((t * 4 + kc) * 4 + quad) * 16 + m16)];
                acc[t] = __builtin_amdgcn_mfma_f32_16x16x32_bf16(af[kc], bh, acc[t], 0, 0, 0);
            }
        }
#pragma unroll
        for (int t = 0; t < 8; t++) {
#pragma unroll
            for (int r = 0; r < 4; r++) {
                int row = rowstart + 16 * w + quad * 4 + r;
                unsigned int us = f2bf(acc[t][r]);
                unsigned int other = (unsigned int)__shfl_xor((int)us, 1);
                if (((m16 & 1) == 0) && row < N)
                    C[(size_t)row * 64 + t * 8 + (m16 >> 1)] = us | (other << 16);
            }
        }
    } else {
        int bb = b - gb;
        if (bb < 8) {
            int fid = bb * 256 + tid;
            int m = fid & 15;
            int quad = (fid >> 4) & 3;
            int kc = (fid >> 6) & 3;
            int t = fid >> 8;
            int n = t * 16 + m;
            int k0 = kc * 32 + quad * 8;
            unsigned short r[8];
#pragma unroll
            for (int j = 0; j < 8; j++) r[j] = f2bf(W2[(k0 + j) * 128 + n]);
            uint4 v;
            v.x = (unsigned int)r[0] | ((unsigned int)r[1] << 16);
            v.y = (unsigned int)r[2] | ((unsigned int)r[3] << 16);
            v.z = (unsigned int)r[4] | ((unsigned int)r[5] << 16);
            v.w = (unsigned int)r[6] | ((unsigned int)r[7] << 16);
            ((uint4*)Wf2)[fid] = v;
        } else {
            int e = (bb - 8) * 256 + tid;
            if (e < E) atomicAdd(&deg[dst[e]], 1);
        }
    }
}

// ---------------- fused scan + finalize: decoupled lookback (R9-verified, ~-20us) ----------
// nscan <= 256 blocks, all co-resident on 256 CUs -> spin is deadlock-free. Each block
// publishes (aggregate | 1<<31) via one device-scope atomicExch into memset-zeroed
// flagagg[], lane-parallel spins on predecessors, LDS-reduces, writes ptr/fill/dinv.
__global__ __launch_bounds__(256) void scanfin_kernel(const int* __restrict__ deg,
                                                      unsigned int* __restrict__ flagagg,
                                                      int* __restrict__ ptr,
                                                      int* __restrict__ fill,
                                                      float* __restrict__ dinv, int N, int E) {
    __shared__ int sm[256];
    int tid = threadIdx.x;
    int blk = blockIdx.x;
    int i = blk * 256 + tid;
    int v = (i < N) ? deg[i] : 0;
    if (i < N) dinv[i] = 1.0f / sqrtf((float)v + 1.0f);
    sm[tid] = v;
    __syncthreads();
    for (int off = 1; off < 256; off <<= 1) {
        int t = (tid >= off) ? sm[tid - off] : 0;
        __syncthreads();
        sm[tid] += t;
        __syncthreads();
    }
    int incl = sm[tid];
    if (tid == 0)
        atomicExch(&flagagg[blk], (unsigned int)sm[255] | 0x80000000u);
    __syncthreads();
    unsigned int a = 0;
    if (tid < blk) {
        unsigned int w;
        do {
            w = (unsigned int)atomicAdd((int*)&flagagg[tid], 0);
        } while (!(w & 0x80000000u));
        a = w & 0x7fffffffu;
    }
    sm[tid] = (int)a;
    __syncthreads();
    for (int off = 128; off > 0; off >>= 1) {
        if (tid < off) sm[tid] += sm[tid + off];
        __syncthreads();
    }
    int blockoff = sm[0];
    if (i < N) {
        int p = incl - v + blockoff;  // exclusive prefix
        ptr[i] = p;
        fill[i] = p;  // scatter cursor
        if (i == N - 1) ptr[N] = E;
    }
}

// ---------------- scatter edges into CSR by dst; packed (src, coef) int2 ----------------
__global__ void scatter_kernel(const int* __restrict__ src, const int* __restrict__ dst,
                               int* __restrict__ fill, const float* __restrict__ dinv,
                               int2* __restrict__ csr_edge, int E) {
    int e = blockIdx.x * blockDim.x + threadIdx.x;
    if (e < E) {
        int d = dst[e];
        int s = src[e];
        int pos = atomicAdd(&fill[d], 1);
        float coef = dinv[s] * dinv[d];
        csr_edge[pos] = make_int2(s, __float_as_int(coef));
    }
}

#define ACC8(v, c)                                                         \
    a0 += bf2f((v).x & 0xffffu) * (c); a1 += bf2f((v).x >> 16) * (c);      \
    a2 += bf2f((v).y & 0xffffu) * (c); a3 += bf2f((v).y >> 16) * (c);      \
    a4 += bf2f((v).z & 0xffffu) * (c); a5 += bf2f((v).z >> 16) * (c);      \
    a6 += bf2f((v).w & 0xffffu) * (c); a7 += bf2f((v).w >> 16) * (c);

// ---------------- FUSED combine(layer1) + gemm2 (R8-verified) ----------------
__global__ __launch_bounds__(256) void combine_gemm_kernel(
        const uint4* __restrict__ h4,       // G1 = x@W1 rows (packed bf16)
        const int* __restrict__ ptr,
        const int2* __restrict__ csr_edge,
        const float* __restrict__ dinv,
        const float* __restrict__ b,        // b1
        const uint4* __restrict__ Wf2,      // fragment-order W2 image
        unsigned int* __restrict__ C,       // out: (h1 @ W2) rows, packed bf16
        int N) {
    __shared__ int2 smeta[4][64];           // 2 KB edge strips
    __shared__ unsigned int rowt[16 * 68];  // 16 rows x 272 B padded h1 tile (4.25 KB)
    int wave = threadIdx.x >> 6;
    int lane = threadIdx.x & 63;
    int q = lane >> 4;
    int l16 = lane & 15;
    int bb = blockIdx.x * 16;
    int nb = bb + wave * 4;
    int node = nb + q;
    bool valid = node < N;

    if (nb < N) {  // predicated (no return: barrier below needs all waves)
        int wlo = ptr[nb];
        int whi = ptr[min(nb + 4, N)];
        int lo = valid ? ptr[node] : 0;
        int hi = valid ? ptr[node + 1] : 0;

        float di = valid ? dinv[node] : 0.f;
        uint4 sv = valid ? h4[(size_t)node * 16 + l16] : make_uint4(0u, 0u, 0u, 0u);
        float4 bv0 = ((const float4*)b)[l16 * 2];
        float4 bv1 = ((const float4*)b)[l16 * 2 + 1];

        float a0 = 0.f, a1 = 0.f, a2 = 0.f, a3 = 0.f, a4 = 0.f, a5 = 0.f, a6 = 0.f, a7 = 0.f;

#pragma unroll 1
        for (int base = wlo; base < whi; base += 64) {
            if (base + lane < whi) smeta[wave][lane] = csr_edge[base + lane];
            // wave-private strip: same-wave DS ordering suffices, no barrier
            int s = max(lo, base);
            int e = min(hi, base + 64);
            int j = s;
#pragma unroll 1
            for (; j + 3 < e; j += 4) {
                int k = j - base;
                int2 e0 = smeta[wave][k];
                int2 e1 = smeta[wave][k + 1];
                int2 e2 = smeta[wave][k + 2];
                int2 e3 = smeta[wave][k + 3];
                uint4 v0 = h4[(size_t)e0.x * 16 + l16];
                uint4 v1 = h4[(size_t)e1.x * 16 + l16];
                uint4 v2 = h4[(size_t)e2.x * 16 + l16];
                uint4 v3 = h4[(size_t)e3.x * 16 + l16];
                float c0 = __int_as_float(e0.y);
                float c1 = __int_as_float(e1.y);
                float c2 = __int_as_float(e2.y);
                float c3 = __int_as_float(e3.y);
                ACC8(v0, c0)
                ACC8(v1, c1)
                ACC8(v2, c2)
                ACC8(v3, c3)
            }
#pragma unroll 1
            for (; j < e; j++) {
                int k = j - base;
                int2 e0 = smeta[wave][k];
                uint4 v0 = h4[(size_t)e0.x * 16 + l16];
                float c0 = __int_as_float(e0.y);
                ACC8(v0, c0)
            }
        }

        if (valid) {
            float dd = di * di;
            float v0 = a0 + bf2f(sv.x & 0xffffu) * dd + bv0.x;
            float v1 = a1 + bf2f(sv.x >> 16) * dd + bv0.y;
            float v2 = a2 + bf2f(sv.y & 0xffffu) * dd + bv0.z;
            float v3 = a3 + bf2f(sv.y >> 16) * dd + bv0.w;
            float v4 = a4 + bf2f(sv.z & 0xffffu) * dd + bv1.x;
            float v5 = a5 + bf2f(sv.z >> 16) * dd + bv1.y;
            float v6 = a6 + bf2f(sv.w & 0xffffu) * dd + bv1.z;
            float v7 = a7 + bf2f(sv.w >> 16) * dd + bv1.w;
            v0 = (v0 >= 0.f) ? v0 : NEG * v0;
            v1 = (v1 >= 0.f) ? v1 : NEG * v1;
            v2 = (v2 >= 0.f) ? v2 : NEG * v2;
            v3 = (v3 >= 0.f) ? v3 : NEG * v3;
            v4 = (v4 >= 0.f) ? v4 : NEG * v4;
            v5 = (v5 >= 0.f) ? v5 : NEG * v5;
            v6 = (v6 >= 0.f) ? v6 : NEG * v6;
            v7 = (v7 >= 0.f) ? v7 : NEG * v7;
            unsigned int* p = &rowt[(wave * 4 + q) * 68 + l16 * 4];
            p[0] = (unsigned int)f2bf(v0) | ((unsigned int)f2bf(v1) << 16);
            p[1] = (unsigned int)f2bf(v2) | ((unsigned int)f2bf(v3) << 16);
            p[2] = (unsigned int)f2bf(v4) | ((unsigned int)f2bf(v5) << 16);
            p[3] = (unsigned int)f2bf(v6) | ((unsigned int)f2bf(v7) << 16);
        }
    }
    __syncthreads();

    // ---- phase 2: 16x128 GEMM tile, h1(LDS) @ W2(global image) ----
#pragma unroll
    for (int tt = 0; tt < 2; tt++) {
        int t = wave * 2 + tt;
        f32x4 acc = (f32x4){0.f, 0.f, 0.f, 0.f};
#pragma unroll
        for (int kc = 0; kc < 4; kc++) {
            bf16x8 a = *(const bf16x8*)&rowt[l16 * 68 + kc * 16 + q * 4];
            bf16x8 bh = *(const bf16x8*)&Wf2[((t * 4 + kc) * 4 + q) * 16 + l16];
            acc = __builtin_amdgcn_mfma_f32_16x16x32_bf16(a, bh, acc, 0, 0, 0);
        }
#pragma unroll
        for (int r = 0; r < 4; r++) {
            int row = bb + q * 4 + r;
            unsigned int us = f2bf(acc[r]);
            unsigned int other = (unsigned int)__shfl_xor((int)us, 1);
            if (((l16 & 1) == 0) && row < N)
                C[(size_t)row * 64 + t * 8 + (l16 >> 1)] = us | (other << 16);
        }
    }
}

// ---------------- gather + self-loop + bias + leaky_relu (layer 2; R1-verified) -------------
__global__ __launch_bounds__(256) void combine_kernel(const uint4* __restrict__ h4,
                                                      const int* __restrict__ ptr,
                                                      const int2* __restrict__ csr_edge,
                                                      const float* __restrict__ dinv,
                                                      const float* __restrict__ b,
                                                      uint4* __restrict__ out4, int N) {
    __shared__ int2 smeta[4][64];
    int wave = threadIdx.x >> 6;
    int lane = threadIdx.x & 63;
    int q = lane >> 4;
    int l16 = lane & 15;
    int nb = blockIdx.x * 16 + wave * 4;
    if (nb >= N) return;  // wave-uniform exit; kernel uses no barriers
    int node = nb + q;
    bool valid = node < N;

    int wlo = ptr[nb];
    int whi = ptr[min(nb + 4, N)];
    int lo = valid ? ptr[node] : 0;
    int hi = valid ? ptr[node + 1] : 0;

    float di = valid ? dinv[node] : 0.f;
    uint4 sv = valid ? h4[(size_t)node * 16 + l16] : make_uint4(0u, 0u, 0u, 0u);
    float4 bv0 = ((const float4*)b)[l16 * 2];
    float4 bv1 = ((const float4*)b)[l16 * 2 + 1];

    float a0 = 0.f, a1 = 0.f, a2 = 0.f, a3 = 0.f, a4 = 0.f, a5 = 0.f, a6 = 0.f, a7 = 0.f;

#pragma unroll 1
    for (int base = wlo; base < whi; base += 64) {
        if (base + lane < whi) smeta[wave][lane] = csr_edge[base + lane];
        int s = max(lo, base);
        int e = min(hi, base + 64);
        int j = s;
#pragma unroll 1
        for (; j + 3 < e; j += 4) {
            int k = j - base;
            int2 e0 = smeta[wave][k];
            int2 e1 = smeta[wave][k + 1];
            int2 e2 = smeta[wave][k + 2];
            int2 e3 = smeta[wave][k + 3];
            uint4 v0 = h4[(size_t)e0.x * 16 + l16];
            uint4 v1 = h4[(size_t)e1.x * 16 + l16];
            uint4 v2 = h4[(size_t)e2.x * 16 + l16];
            uint4 v3 = h4[(size_t)e3.x * 16 + l16];
            float c0 = __int_as_float(e0.y);
            float c1 = __int_as_float(e1.y);
            float c2 = __int_as_float(e2.y);
            float c3 = __int_as_float(e3.y);
            ACC8(v0, c0)
            ACC8(v1, c1)
            ACC8(v2, c2)
            ACC8(v3, c3)
        }
#pragma unroll 1
        for (; j < e; j++) {
            int k = j - base;
            int2 e0 = smeta[wave][k];
            uint4 v0 = h4[(size_t)e0.x * 16 + l16];
            float c0 = __int_as_float(e0.y);
            ACC8(v0, c0)
        }
    }

    if (!valid) return;
    float dd = di * di;
    float v0 = a0 + bf2f(sv.x & 0xffffu) * dd + bv0.x;
    float v1 = a1 + bf2f(sv.x >> 16) * dd + bv0.y;
    float v2 = a2 + bf2f(sv.y & 0xffffu) * dd + bv0.z;
    float v3 = a3 + bf2f(sv.y >> 16) * dd + bv0.w;
    float v4 = a4 + bf2f(sv.z & 0xffffu) * dd + bv1.x;
    float v5 = a5 + bf2f(sv.z >> 16) * dd + bv1.y;
    float v6 = a6 + bf2f(sv.w & 0xffffu) * dd + bv1.z;
    float v7 = a7 + bf2f(sv.w >> 16) * dd + bv1.w;
    v0 = (v0 >= 0.f) ? v0 : NEG * v0;
    v1 = (v1 >= 0.f) ? v1 : NEG * v1;
    v2 = (v2 >= 0.f) ? v2 : NEG * v2;
    v3 = (v3 >= 0.f) ? v3 : NEG * v3;
    v4 = (v4 >= 0.f) ? v4 : NEG * v4;
    v5 = (v5 >= 0.f) ? v5 : NEG * v5;
    v6 = (v6 >= 0.f) ? v6 : NEG * v6;
    v7 = (v7 >= 0.f) ? v7 : NEG * v7;
    uint4 pv;
    pv.x = (unsigned int)f2bf(v0) | ((unsigned int)f2bf(v1) << 16);
    pv.y = (unsigned int)f2bf(v2) | ((unsigned int)f2bf(v3) << 16);
    pv.z = (unsigned int)f2bf(v4) | ((unsigned int)f2bf(v5) << 16);
    pv.w = (unsigned int)f2bf(v6) | ((unsigned int)f2bf(v7) << 16);
    out4[(size_t)node * 16 + l16] = pv;
}

// ---------------- pool: node-parallel chunked accumulate (R8-proven, 391 blocks) ------------
// R9 lesson: one-block-per-graph pooling = 1 wave/CU = 67us latency chain. Parallelism first.
#define PROWS 128
__global__ void pool_accum_kernel(const unsigned int* __restrict__ a2,
                                  const int* __restrict__ batch,
                                  float* __restrict__ pooled, int N) {
    int wave = threadIdx.x >> 6;
    int lane = threadIdx.x & 63;
    int start = blockIdx.x * PROWS;
    int end = start + PROWS;
    if (end > N) end = N;
    float s0 = 0.f, s1 = 0.f;
    int curg = -1;
    for (int r = start + wave; r < end; r += 4) {
        int g = batch[r];  // wave-uniform (sorted batch)
        if (g != curg) {
            if (curg >= 0) {
                atomicAdd(&pooled[curg * D + 2 * lane], s0);
                atomicAdd(&pooled[curg * D + 2 * lane + 1], s1);
            }
            curg = g;
            s0 = 0.f;
            s1 = 0.f;
        }
        unsigned int v = a2[(size_t)r * 64 + lane];
        s0 += bf2f(v & 0xffffu);
        s1 += bf2f(v >> 16);
    }
    if (curg >= 0) {
        atomicAdd(&pooled[curg * D + 2 * lane], s0);
        atomicAdd(&pooled[curg * D + 2 * lane + 1], s1);
    }
}

// ---------------- final linear ----------------
__global__ void final_kernel(const float* __restrict__ pooled, const int* __restrict__ batch,
                             const float* __restrict__ Wl, const float* __restrict__ bl,
                             float* __restrict__ out, int N) {
    int t = blockIdx.x * blockDim.x + threadIdx.x;
    if (t >= NG * NC) return;
    int g = t >> 4, c = t & 15;
    int l = 0, h = N;
    while (l < h) { int m = (l + h) >> 1; if (batch[m] < g) l = m + 1; else h = m; }
    int lo = l;
    h = N;
    while (l < h) { int m = (l + h) >> 1; if (batch[m] < g + 1) l = m + 1; else h = m; }
    int cnt = l - lo;
    float inv = 1.0f / (float)(cnt > 0 ? cnt : 1);
    float dot = 0.f;
    for (int k = 0; k < D; k++) dot += pooled[g * D + k] * Wl[k * NC + c];
    out[t] = dot * inv + bl[c];
}

extern "C" void kernel_launch(void* const* d_in, const int* in_sizes, int n_in,
                              void* d_out, int out_size, void* d_ws, size_t ws_size,
                              hipStream_t stream) {
    const float* x = (const float*)d_in[0];
    const int* ei = (const int*)d_in[1];
    const int* batch = (const int*)d_in[2];
    const float* W1 = (const float*)d_in[3];
    const float* b1 = (const float*)d_in[4];
    const float* W2 = (const float*)d_in[5];
    const float* b2 = (const float*)d_in[6];
    const float* Wlin = (const float*)d_in[7];
    const float* bl = (const float*)d_in[8];
    float* out = (float*)d_out;

    int N = in_sizes[0] / D;
    int E = in_sizes[1] / 2;
    const int* src = ei;
    const int* dst = ei + E;

    float* ws = (float*)d_ws;
    size_t o = 0;
    unsigned int* bufA = (unsigned int*)(ws + o); o += (size_t)N * 64;  // 12.8 MB
    unsigned int* bufB = (unsigned int*)(ws + o); o += (size_t)N * 64;  // 12.8 MB
    int* deg = (int*)(ws + o);      o += N;       // zeroed by memset (with flagagg+pooled)
    unsigned int* flagagg = (unsigned int*)(ws + o); o += 256;  // zeroed by memset
    float* pooled = ws + o;         o += NG * D;  // zeroed by memset
    int* fill = (int*)(ws + o);     o += N;
    float* dinv = ws + o;           o += N;
    int* csr_ptr = (int*)(ws + o);  o += (N + 4);
    int2* csr_edge = (int2*)(ws + o); o += (size_t)2 * E;
    unsigned short* Wf2 = (unsigned short*)(ws + o); o += 8192;

    // one memset covers deg[N] + flagagg[256] + pooled[NG*D] (contiguous)
    hipMemsetAsync(deg, 0, ((size_t)N + 256 + NG * D) * sizeof(float), stream);

    int tb = 256;
    int nscan = (N + 255) / 256;
    int gblocks = (N + 63) / 64;
    int cblocks = (N + 15) / 16;
    int eblocks = (E + 255) / 256;

    // fused: layer-1 GEMM || {Wf2 image, degree histogram}
    prep_gemm1_kernel<<<gblocks + 8 + eblocks, 256, 0, stream>>>(
        x, W1, (unsigned int*)bufA, gblocks, W2, Wf2, dst, deg, E, N);
    // fused scan+finalize (decoupled lookback)
    scanfin_kernel<<<nscan, 256, 0, stream>>>(deg, flagagg, csr_ptr, fill, dinv, N, E);
    scatter_kernel<<<(E + tb - 1) / tb, tb, 0, stream>>>(src, dst, fill, dinv,
                                                         csr_edge, E);
    // fused combine(layer1)+gemm2: bufA(G1) -> bufB(h1@W2)
    combine_gemm_kernel<<<cblocks, 256, 0, stream>>>((const uint4*)bufA, csr_ptr, csr_edge,
                                                     dinv, b1, (const uint4*)Wf2,
                                                     (unsigned int*)bufB, N);
    // layer-2 combine: bufB -> bufA
    combine_kernel<<<cblocks, 256, 0, stream>>>((const uint4*)bufB, csr_ptr, csr_edge,
                                                dinv, b2, (uint4*)bufA, N);
    // pool + classifier (R8-proven parallel pair)
    pool_accum_kernel<<<(N + PROWS - 1) / PROWS, 256, 0, stream>>>(bufA, batch, pooled, N);
    final_kernel<<<(NG * NC + tb - 1) / tb, tb, 0, stream>>>(pooled, batch, Wlin, bl, out, N);
}

// Round 11
// 228.947 us; speedup vs baseline: 1.1689x; 1.0122x over previous
//
#include <hip/hip_runtime.h>

#define D 128
#define NG 64
#define NC 16
#define NEG 0.1f

typedef __attribute__((ext_vector_type(8))) short bf16x8;
typedef __attribute__((ext_vector_type(4))) float f32x4;

// ---------- bf16 <-> fp32 helpers (bf16 stored as ushort, packed pairs in uint) ----------
__device__ __forceinline__ float bf2f(unsigned int u16) {
    union { unsigned int i; float f; } c;
    c.i = u16 << 16;
    return c.f;
}
__device__ __forceinline__ unsigned short f2bf(float f) {
    union { float f; unsigned int i; } c;
    c.f = f;
    unsigned int i = c.i;
    unsigned int r = (i + 0x7FFFu + ((i >> 16) & 1u)) >> 16;  // RNE
    return (unsigned short)r;
}

// ---------------- fused prep + layer-1 GEMM (R7-verified) ----------------
// blocks [0, gb): layer-1 MFMA GEMM (W1 image built in-block in LDS).
// blocks [gb, gb+8): W2 -> Wf2 fragment-order image. [gb+8, ...): degree histogram.
__global__ __launch_bounds__(256) void prep_gemm1_kernel(
        const float* __restrict__ x, const float* __restrict__ W1,
        unsigned int* __restrict__ C, int gb,
        const float* __restrict__ W2, unsigned short* __restrict__ Wf2,
        const int* __restrict__ dst, int* __restrict__ deg, int E, int N) {
    __shared__ uint4 Ws[2048];  // 32 KB, fragment-order image (gemm blocks only)
    int b = blockIdx.x;
    int tid = threadIdx.x;
    if (b < gb) {
        int w = tid >> 6, lane = tid & 63;
        int quad = lane >> 4, m16 = lane & 15;
        int rowstart = b * 64;
#pragma unroll
        for (int i = 0; i < 8; i++) {
            int fid = tid + 256 * i;
            int fm = fid & 15;
            int fquad = (fid >> 4) & 3;
            int fkc = (fid >> 6) & 3;
            int ft = fid >> 8;
            int n = ft * 16 + fm;
            int k0 = fkc * 32 + fquad * 8;
            unsigned short r[8];
#pragma unroll
            for (int j = 0; j < 8; j++) r[j] = f2bf(W1[(k0 + j) * 128 + n]);
            uint4 v;
            v.x = (unsigned int)r[0] | ((unsigned int)r[1] << 16);
            v.y = (unsigned int)r[2] | ((unsigned int)r[3] << 16);
            v.z = (unsigned int)r[4] | ((unsigned int)r[5] << 16);
            v.w = (unsigned int)r[6] | ((unsigned int)r[7] << 16);
            Ws[fid] = v;
        }

        int arow = rowstart + 16 * w + m16;
        bool valid = arow < N;
        bf16x8 af[4];
#pragma unroll
        for (int kc = 0; kc < 4; kc++) {
            float4 f0 = make_float4(0.f, 0.f, 0.f, 0.f), f1 = f0;
            if (valid) {
                const float4* p = (const float4*)(x + (size_t)arow * 128 + kc * 32 + quad * 8);
                f0 = p[0];
                f1 = p[1];
            }
            bf16x8 a;
            a[0] = (short)f2bf(f0.x); a[1] = (short)f2bf(f0.y);
            a[2] = (short)f2bf(f0.z); a[3] = (short)f2bf(f0.w);
            a[4] = (short)f2bf(f1.x); a[5] = (short)f2bf(f1.y);
            a[6] = (short)f2bf(f1.z); a[7] = (short)f2bf(f1.w);
            af[kc] = a;
        }
        __syncthreads();

        f32x4 acc[8];
#pragma unroll
        for (int t = 0; t < 8; t++) acc[t] = (f32x4){0.f, 0.f, 0.f, 0.f};
#pragma unroll
        for (int t = 0; t < 8; t++) {
#pragma unroll
            for (int kc = 0; kc < 4; kc++) {
                bf16x8 bh = *(const bf16x8*)&Ws[(((t * 4 + kc) * 4 + quad) * 16 + m16)];
                acc[t] = __builtin_amdgcn_mfma_f32_16x16x32_bf16(af[kc], bh, acc[t], 0, 0, 0);
            }
        }
#pragma unroll
        for (int t = 0; t < 8; t++) {
#pragma unroll
            for (int r = 0; r < 4; r++) {
                int row = rowstart + 16 * w + quad * 4 + r;
                unsigned int us = f2bf(acc[t][r]);
                unsigned int other = (unsigned int)__shfl_xor((int)us, 1);
                if (((m16 & 1) == 0) && row < N)
                    C[(size_t)row * 64 + t * 8 + (m16 >> 1)] = us | (other << 16);
            }
        }
    } else {
        int bb = b - gb;
        if (bb < 8) {
            int fid = bb * 256 + tid;
            int m = fid & 15;
            int quad = (fid >> 4) & 3;
            int kc = (fid >> 6) & 3;
            int t = fid >> 8;
            int n = t * 16 + m;
            int k0 = kc * 32 + quad * 8;
            unsigned short r[8];
#pragma unroll
            for (int j = 0; j < 8; j++) r[j] = f2bf(W2[(k0 + j) * 128 + n]);
            uint4 v;
            v.x = (unsigned int)r[0] | ((unsigned int)r[1] << 16);
            v.y = (unsigned int)r[2] | ((unsigned int)r[3] << 16);
            v.z = (unsigned int)r[4] | ((unsigned int)r[5] << 16);
            v.w = (unsigned int)r[6] | ((unsigned int)r[7] << 16);
            ((uint4*)Wf2)[fid] = v;
        } else {
            int e = (bb - 8) * 256 + tid;
            if (e < E) atomicAdd(&deg[dst[e]], 1);
        }
    }
}

// ---------------- scan stage 1 (+ dinv fold) — R8-proven (R10: lookback fusion is +4us) -----
__global__ void scan_block_kernel(const int* __restrict__ deg, int* __restrict__ scan1,
                                  int* __restrict__ blocksum, float* __restrict__ dinv, int N) {
    __shared__ int sm[256];
    int tid = threadIdx.x;
    int i = blockIdx.x * 256 + tid;
    int v = (i < N) ? deg[i] : 0;
    if (i < N) dinv[i] = 1.0f / sqrtf((float)v + 1.0f);
    sm[tid] = v;
    __syncthreads();
    for (int off = 1; off < 256; off <<= 1) {
        int t = (tid >= off) ? sm[tid - off] : 0;
        __syncthreads();
        sm[tid] += t;
        __syncthreads();
    }
    if (i < N) scan1[i] = sm[tid];  // inclusive
    if (tid == 255) blocksum[blockIdx.x] = sm[255];
}

// ---------------- finalize: ptr = exclusive prefix; fill seeded with ptr (scatter cursor) ----
__global__ void finalize_ptr_kernel(const int* __restrict__ deg, const int* __restrict__ scan1,
                                    const int* __restrict__ blocksum, int* __restrict__ ptr,
                                    int* __restrict__ fill, int nb, int N, int E) {
    __shared__ int sm[256];
    int tid = threadIdx.x;
    int v = (tid < nb) ? blocksum[tid] : 0;
    sm[tid] = v;
    __syncthreads();
    for (int off = 1; off < 256; off <<= 1) {
        int t = (tid >= off) ? sm[tid - off] : 0;
        __syncthreads();
        sm[tid] += t;
        __syncthreads();
    }
    int blockoff = (blockIdx.x > 0) ? sm[blockIdx.x - 1] : 0;
    int i = blockIdx.x * 256 + tid;
    if (i < N) {
        int p = scan1[i] - deg[i] + blockoff;
        ptr[i] = p;
        fill[i] = p;  // scatter cursor
        if (i == N - 1) ptr[N] = E;
    }
}

// ---------------- scatter edges into CSR by dst; packed (src, coef) int2 ----------------
__global__ void scatter_kernel(const int* __restrict__ src, const int* __restrict__ dst,
                               int* __restrict__ fill, const float* __restrict__ dinv,
                               int2* __restrict__ csr_edge, int E) {
    int e = blockIdx.x * blockDim.x + threadIdx.x;
    if (e < E) {
        int d = dst[e];
        int s = src[e];
        int pos = atomicAdd(&fill[d], 1);
        float coef = dinv[s] * dinv[d];
        csr_edge[pos] = make_int2(s, __float_as_int(coef));
    }
}

#define ACC8(v, c)                                                         \
    a0 += bf2f((v).x & 0xffffu) * (c); a1 += bf2f((v).x >> 16) * (c);      \
    a2 += bf2f((v).y & 0xffffu) * (c); a3 += bf2f((v).y >> 16) * (c);      \
    a4 += bf2f((v).z & 0xffffu) * (c); a5 += bf2f((v).z >> 16) * (c);      \
    a6 += bf2f((v).w & 0xffffu) * (c); a7 += bf2f((v).w >> 16) * (c);

// ---------------- FUSED combine(layer1) + gemm2 (R8-verified) ----------------
__global__ __launch_bounds__(256) void combine_gemm_kernel(
        const uint4* __restrict__ h4,       // G1 = x@W1 rows (packed bf16)
        const int* __restrict__ ptr,
        const int2* __restrict__ csr_edge,
        const float* __restrict__ dinv,
        const float* __restrict__ b,        // b1
        const uint4* __restrict__ Wf2,      // fragment-order W2 image
        unsigned int* __restrict__ C,       // out: (h1 @ W2) rows, packed bf16
        int N) {
    __shared__ int2 smeta[4][64];           // 2 KB edge strips
    __shared__ unsigned int rowt[16 * 68];  // 16 rows x 272 B padded h1 tile (4.25 KB)
    int wave = threadIdx.x >> 6;
    int lane = threadIdx.x & 63;
    int q = lane >> 4;
    int l16 = lane & 15;
    int bb = blockIdx.x * 16;
    int nb = bb + wave * 4;
    int node = nb + q;
    bool valid = node < N;

    if (nb < N) {  // predicated (no return: barrier below needs all waves)
        int wlo = ptr[nb];
        int whi = ptr[min(nb + 4, N)];
        int lo = valid ? ptr[node] : 0;
        int hi = valid ? ptr[node + 1] : 0;

        float di = valid ? dinv[node] : 0.f;
        uint4 sv = valid ? h4[(size_t)node * 16 + l16] : make_uint4(0u, 0u, 0u, 0u);
        float4 bv0 = ((const float4*)b)[l16 * 2];
        float4 bv1 = ((const float4*)b)[l16 * 2 + 1];

        float a0 = 0.f, a1 = 0.f, a2 = 0.f, a3 = 0.f, a4 = 0.f, a5 = 0.f, a6 = 0.f, a7 = 0.f;

#pragma unroll 1
        for (int base = wlo; base < whi; base += 64) {
            if (base + lane < whi) smeta[wave][lane] = csr_edge[base + lane];
            // wave-private strip: same-wave DS ordering suffices, no barrier
            int s = max(lo, base);
            int e = min(hi, base + 64);
            int j = s;
#pragma unroll 1
            for (; j + 3 < e; j += 4) {
                int k = j - base;
                int2 e0 = smeta[wave][k];
                int2 e1 = smeta[wave][k + 1];
                int2 e2 = smeta[wave][k + 2];
                int2 e3 = smeta[wave][k + 3];
                uint4 v0 = h4[(size_t)e0.x * 16 + l16];
                uint4 v1 = h4[(size_t)e1.x * 16 + l16];
                uint4 v2 = h4[(size_t)e2.x * 16 + l16];
                uint4 v3 = h4[(size_t)e3.x * 16 + l16];
                float c0 = __int_as_float(e0.y);
                float c1 = __int_as_float(e1.y);
                float c2 = __int_as_float(e2.y);
                float c3 = __int_as_float(e3.y);
                ACC8(v0, c0)
                ACC8(v1, c1)
                ACC8(v2, c2)
                ACC8(v3, c3)
            }
#pragma unroll 1
            for (; j < e; j++) {
                int k = j - base;
                int2 e0 = smeta[wave][k];
                uint4 v0 = h4[(size_t)e0.x * 16 + l16];
                float c0 = __int_as_float(e0.y);
                ACC8(v0, c0)
            }
        }

        if (valid) {
            float dd = di * di;
            float v0 = a0 + bf2f(sv.x & 0xffffu) * dd + bv0.x;
            float v1 = a1 + bf2f(sv.x >> 16) * dd + bv0.y;
            float v2 = a2 + bf2f(sv.y & 0xffffu) * dd + bv0.z;
            float v3 = a3 + bf2f(sv.y >> 16) * dd + bv0.w;
            float v4 = a4 + bf2f(sv.z & 0xffffu) * dd + bv1.x;
            float v5 = a5 + bf2f(sv.z >> 16) * dd + bv1.y;
            float v6 = a6 + bf2f(sv.w & 0xffffu) * dd + bv1.z;
            float v7 = a7 + bf2f(sv.w >> 16) * dd + bv1.w;
            v0 = (v0 >= 0.f) ? v0 : NEG * v0;
            v1 = (v1 >= 0.f) ? v1 : NEG * v1;
            v2 = (v2 >= 0.f) ? v2 : NEG * v2;
            v3 = (v3 >= 0.f) ? v3 : NEG * v3;
            v4 = (v4 >= 0.f) ? v4 : NEG * v4;
            v5 = (v5 >= 0.f) ? v5 : NEG * v5;
            v6 = (v6 >= 0.f) ? v6 : NEG * v6;
            v7 = (v7 >= 0.f) ? v7 : NEG * v7;
            unsigned int* p = &rowt[(wave * 4 + q) * 68 + l16 * 4];
            p[0] = (unsigned int)f2bf(v0) | ((unsigned int)f2bf(v1) << 16);
            p[1] = (unsigned int)f2bf(v2) | ((unsigned int)f2bf(v3) << 16);
            p[2] = (unsigned int)f2bf(v4) | ((unsigned int)f2bf(v5) << 16);
            p[3] = (unsigned int)f2bf(v6) | ((unsigned int)f2bf(v7) << 16);
        }
    }
    __syncthreads();

    // ---- phase 2: 16x128 GEMM tile, h1(LDS) @ W2(global image) ----
#pragma unroll
    for (int tt = 0; tt < 2; tt++) {
        int t = wave * 2 + tt;
        f32x4 acc = (f32x4){0.f, 0.f, 0.f, 0.f};
#pragma unroll
        for (int kc = 0; kc < 4; kc++) {
            bf16x8 a = *(const bf16x8*)&rowt[l16 * 68 + kc * 16 + q * 4];
            bf16x8 bh = *(const bf16x8*)&Wf2[((t * 4 + kc) * 4 + q) * 16 + l16];
            acc = __builtin_amdgcn_mfma_f32_16x16x32_bf16(a, bh, acc, 0, 0, 0);
        }
#pragma unroll
        for (int r = 0; r < 4; r++) {
            int row = bb + q * 4 + r;
            unsigned int us = f2bf(acc[r]);
            unsigned int other = (unsigned int)__shfl_xor((int)us, 1);
            if (((l16 & 1) == 0) && row < N)
                C[(size_t)row * 64 + t * 8 + (l16 >> 1)] = us | (other << 16);
        }
    }
}

// ---------------- gather + self-loop + bias + leaky_relu (layer 2; R1-verified) -------------
__global__ __launch_bounds__(256) void combine_kernel(const uint4* __restrict__ h4,
                                                      const int* __restrict__ ptr,
                                                      const int2* __restrict__ csr_edge,
                                                      const float* __restrict__ dinv,
                                                      const float* __restrict__ b,
                                                      uint4* __restrict__ out4, int N) {
    __shared__ int2 smeta[4][64];
    int wave = threadIdx.x >> 6;
    int lane = threadIdx.x & 63;
    int q = lane >> 4;
    int l16 = lane & 15;
    int nb = blockIdx.x * 16 + wave * 4;
    if (nb >= N) return;  // wave-uniform exit; kernel uses no barriers
    int node = nb + q;
    bool valid = node < N;

    int wlo = ptr[nb];
    int whi = ptr[min(nb + 4, N)];
    int lo = valid ? ptr[node] : 0;
    int hi = valid ? ptr[node + 1] : 0;

    float di = valid ? dinv[node] : 0.f;
    uint4 sv = valid ? h4[(size_t)node * 16 + l16] : make_uint4(0u, 0u, 0u, 0u);
    float4 bv0 = ((const float4*)b)[l16 * 2];
    float4 bv1 = ((const float4*)b)[l16 * 2 + 1];

    float a0 = 0.f, a1 = 0.f, a2 = 0.f, a3 = 0.f, a4 = 0.f, a5 = 0.f, a6 = 0.f, a7 = 0.f;

#pragma unroll 1
    for (int base = wlo; base < whi; base += 64) {
        if (base + lane < whi) smeta[wave][lane] = csr_edge[base + lane];
        int s = max(lo, base);
        int e = min(hi, base + 64);
        int j = s;
#pragma unroll 1
        for (; j + 3 < e; j += 4) {
            int k = j - base;
            int2 e0 = smeta[wave][k];
            int2 e1 = smeta[wave][k + 1];
            int2 e2 = smeta[wave][k + 2];
            int2 e3 = smeta[wave][k + 3];
            uint4 v0 = h4[(size_t)e0.x * 16 + l16];
            uint4 v1 = h4[(size_t)e1.x * 16 + l16];
            uint4 v2 = h4[(size_t)e2.x * 16 + l16];
            uint4 v3 = h4[(size_t)e3.x * 16 + l16];
            float c0 = __int_as_float(e0.y);
            float c1 = __int_as_float(e1.y);
            float c2 = __int_as_float(e2.y);
            float c3 = __int_as_float(e3.y);
            ACC8(v0, c0)
            ACC8(v1, c1)
            ACC8(v2, c2)
            ACC8(v3, c3)
        }
#pragma unroll 1
        for (; j < e; j++) {
            int k = j - base;
            int2 e0 = smeta[wave][k];
            uint4 v0 = h4[(size_t)e0.x * 16 + l16];
            float c0 = __int_as_float(e0.y);
            ACC8(v0, c0)
        }
    }

    if (!valid) return;
    float dd = di * di;
    float v0 = a0 + bf2f(sv.x & 0xffffu) * dd + bv0.x;
    float v1 = a1 + bf2f(sv.x >> 16) * dd + bv0.y;
    float v2 = a2 + bf2f(sv.y & 0xffffu) * dd + bv0.z;
    float v3 = a3 + bf2f(sv.y >> 16) * dd + bv0.w;
    float v4 = a4 + bf2f(sv.z & 0xffffu) * dd + bv1.x;
    float v5 = a5 + bf2f(sv.z >> 16) * dd + bv1.y;
    float v6 = a6 + bf2f(sv.w & 0xffffu) * dd + bv1.z;
    float v7 = a7 + bf2f(sv.w >> 16) * dd + bv1.w;
    v0 = (v0 >= 0.f) ? v0 : NEG * v0;
    v1 = (v1 >= 0.f) ? v1 : NEG * v1;
    v2 = (v2 >= 0.f) ? v2 : NEG * v2;
    v3 = (v3 >= 0.f) ? v3 : NEG * v3;
    v4 = (v4 >= 0.f) ? v4 : NEG * v4;
    v5 = (v5 >= 0.f) ? v5 : NEG * v5;
    v6 = (v6 >= 0.f) ? v6 : NEG * v6;
    v7 = (v7 >= 0.f) ? v7 : NEG * v7;
    uint4 pv;
    pv.x = (unsigned int)f2bf(v0) | ((unsigned int)f2bf(v1) << 16);
    pv.y = (unsigned int)f2bf(v2) | ((unsigned int)f2bf(v3) << 16);
    pv.z = (unsigned int)f2bf(v4) | ((unsigned int)f2bf(v5) << 16);
    pv.w = (unsigned int)f2bf(v6) | ((unsigned int)f2bf(v7) << 16);
    out4[(size_t)node * 16 + l16] = pv;
}

// ---------------- pool: node-parallel chunked accumulate (R8-proven, 391 blocks) ------------
// R9 lesson: one-block-per-graph pooling = 1 wave/CU = 67us latency chain. Parallelism first.
#define PROWS 128
__global__ void pool_accum_kernel(const unsigned int* __restrict__ a2,
                                  const int* __restrict__ batch,
                                  float* __restrict__ pooled, int N) {
    int wave = threadIdx.x >> 6;
    int lane = threadIdx.x & 63;
    int start = blockIdx.x * PROWS;
    int end = start + PROWS;
    if (end > N) end = N;
    float s0 = 0.f, s1 = 0.f;
    int curg = -1;
    for (int r = start + wave; r < end; r += 4) {
        int g = batch[r];  // wave-uniform (sorted batch)
        if (g != curg) {
            if (curg >= 0) {
                atomicAdd(&pooled[curg * D + 2 * lane], s0);
                atomicAdd(&pooled[curg * D + 2 * lane + 1], s1);
            }
            curg = g;
            s0 = 0.f;
            s1 = 0.f;
        }
        unsigned int v = a2[(size_t)r * 64 + lane];
        s0 += bf2f(v & 0xffffu);
        s1 += bf2f(v >> 16);
    }
    if (curg >= 0) {
        atomicAdd(&pooled[curg * D + 2 * lane], s0);
        atomicAdd(&pooled[curg * D + 2 * lane + 1], s1);
    }
}

// ---------------- final linear ----------------
__global__ void final_kernel(const float* __restrict__ pooled, const int* __restrict__ batch,
                             const float* __restrict__ Wl, const float* __restrict__ bl,
                             float* __restrict__ out, int N) {
    int t = blockIdx.x * blockDim.x + threadIdx.x;
    if (t >= NG * NC) return;
    int g = t >> 4, c = t & 15;
    int l = 0, h = N;
    while (l < h) { int m = (l + h) >> 1; if (batch[m] < g) l = m + 1; else h = m; }
    int lo = l;
    h = N;
    while (l < h) { int m = (l + h) >> 1; if (batch[m] < g + 1) l = m + 1; else h = m; }
    int cnt = l - lo;
    float inv = 1.0f / (float)(cnt > 0 ? cnt : 1);
    float dot = 0.f;
    for (int k = 0; k < D; k++) dot += pooled[g * D + k] * Wl[k * NC + c];
    out[t] = dot * inv + bl[c];
}

extern "C" void kernel_launch(void* const* d_in, const int* in_sizes, int n_in,
                              void* d_out, int out_size, void* d_ws, size_t ws_size,
                              hipStream_t stream) {
    const float* x = (const float*)d_in[0];
    const int* ei = (const int*)d_in[1];
    const int* batch = (const int*)d_in[2];
    const float* W1 = (const float*)d_in[3];
    const float* b1 = (const float*)d_in[4];
    const float* W2 = (const float*)d_in[5];
    const float* b2 = (const float*)d_in[6];
    const float* Wlin = (const float*)d_in[7];
    const float* bl = (const float*)d_in[8];
    float* out = (float*)d_out;

    int N = in_sizes[0] / D;
    int E = in_sizes[1] / 2;
    const int* src = ei;
    const int* dst = ei + E;

    float* ws = (float*)d_ws;
    size_t o = 0;
    unsigned int* bufA = (unsigned int*)(ws + o); o += (size_t)N * 64;  // 12.8 MB
    unsigned int* bufB = (unsigned int*)(ws + o); o += (size_t)N * 64;  // 12.8 MB
    int* deg = (int*)(ws + o);      o += N;       // zeroed by memset (with pooled)
    float* pooled = ws + o;         o += NG * D;  // zeroed by memset
    int* fill = (int*)(ws + o);     o += N;
    float* dinv = ws + o;           o += N;
    int* scan1 = (int*)(ws + o);    o += N;
    int* blocksum = (int*)(ws + o); o += 256;
    int* csr_ptr = (int*)(ws + o);  o += (N + 4);
    int2* csr_edge = (int2*)(ws + o); o += (size_t)2 * E;
    unsigned short* Wf2 = (unsigned short*)(ws + o); o += 8192;

    // one memset covers deg[N] + pooled[NG*D] (contiguous)
    hipMemsetAsync(deg, 0, ((size_t)N + NG * D) * sizeof(float), stream);

    int tb = 256;
    int nscan = (N + 255) / 256;
    int gblocks = (N + 63) / 64;
    int cblocks = (N + 15) / 16;
    int eblocks = (E + 255) / 256;

    // fused: layer-1 GEMM || {Wf2 image, degree histogram}
    prep_gemm1_kernel<<<gblocks + 8 + eblocks, 256, 0, stream>>>(
        x, W1, (unsigned int*)bufA, gblocks, W2, Wf2, dst, deg, E, N);
    scan_block_kernel<<<nscan, 256, 0, stream>>>(deg, scan1, blocksum, dinv, N);
    finalize_ptr_kernel<<<nscan, 256, 0, stream>>>(deg, scan1, blocksum, csr_ptr, fill,
                                                   nscan, N, E);
    scatter_kernel<<<(E + tb - 1) / tb, tb, 0, stream>>>(src, dst, fill, dinv,
                                                         csr_edge, E);
    // fused combine(layer1)+gemm2: bufA(G1) -> bufB(h1@W2)
    combine_gemm_kernel<<<cblocks, 256, 0, stream>>>((const uint4*)bufA, csr_ptr, csr_edge,
                                                     dinv, b1, (const uint4*)Wf2,
                                                     (unsigned int*)bufB, N);
    // layer-2 combine: bufB -> bufA
    combine_kernel<<<cblocks, 256, 0, stream>>>((const uint4*)bufB, csr_ptr, csr_edge,
                                                dinv, b2, (uint4*)bufA, N);
    // pool + classifier (R8-proven parallel pair)
    pool_accum_kernel<<<(N + PROWS - 1) / PROWS, 256, 0, stream>>>(bufA, batch, pooled, N);
    final_kernel<<<(NG * NC + tb - 1) / tb, tb, 0, stream>>>(pooled, batch, Wlin, bl, out, N);
}